// Round 1
// baseline (4487.993 us; speedup 1.0000x reference)
//
#include <hip/hip_runtime.h>
#include <hip/hip_bf16.h>
#include <stdint.h>

typedef __bf16 bf16;
typedef bf16 bf16x8 __attribute__((ext_vector_type(8)));
typedef bf16 bf16x4 __attribute__((ext_vector_type(4)));
typedef float f32x4 __attribute__((ext_vector_type(4)));

#define NB 8
#define NH 36
#define NW 100
#define YS 44
#define XSZ 108
#define PIX 28800

static_assert(sizeof(bf16) == 2, "bf16 size");

// ---------------- workspace layout (all chunks 16B-aligned) ----------------
static constexpr size_t OFF_XP = 0;                                   // bf16 [8][44][108][512] padded NHWC input
static constexpr size_t SZ_XP  = (size_t)NB*YS*XSZ*512*2;             // 38,928,384
static constexpr size_t OFF_HP = OFF_XP + SZ_XP;                      // bf16 [8][44][108][128] padded NHWC h2 (msg-pass state)
static constexpr size_t SZ_HP  = (size_t)NB*YS*XSZ*128*2;             // 9,732,096
static constexpr size_t OFF_A1 = OFF_HP + SZ_HP;                      // bf16 [1024][4608]  k=(ky*3+kx)*512+ci
static constexpr size_t SZ_A1  = (size_t)1024*4608*2;
static constexpr size_t OFF_A2 = OFF_A1 + SZ_A1;                      // bf16 [128][1024]
static constexpr size_t SZ_A2  = (size_t)128*1024*2;
static constexpr size_t OFF_AW = OFF_A2 + SZ_A2;                      // bf16 [4][9][128][128]  (t, co, ci)
static constexpr size_t SZ_AW  = (size_t)4*9*128*128*2;
static constexpr size_t OFF_H1 = OFF_AW + SZ_AW;                      // bf16 [28800][1024] NHWC h1
static constexpr size_t SZ_H1  = (size_t)PIX*1024*2;
static constexpr size_t OFF_S1 = OFF_H1 + SZ_H1;                      // f32 [1024]
static constexpr size_t OFF_T1 = OFF_S1 + 4096;                       // f32 [1024]
static constexpr size_t OFF_S2 = OFF_T1 + 4096;                       // f32 [128]
static constexpr size_t OFF_T2 = OFF_S2 + 512;                        // f32 [128]
static constexpr size_t OFF_H5 = OFF_T2 + 512;                        // f32 [8][5][36][100] conv3 out
static constexpr size_t SZ_H5  = (size_t)NB*5*3600*4;                 // 576000 floats -> 2,304,000 B
static constexpr size_t OFF_P  = OFF_H5 + SZ_H5;                      // f32 [8][5][36][100] softmax
static constexpr size_t OFF_F  = OFF_P + SZ_H5;                       // f32 [8][4500] pooled
static constexpr size_t OFF_G  = OFF_F + 144128;                      // f32 [8][128] fc1 out

// ---------------- prep kernels ----------------
__global__ __launch_bounds__(256) void zero_k(uint4* __restrict__ p, int n) {
    int i = blockIdx.x * 256 + threadIdx.x;
    if (i < n) p[i] = uint4{0u, 0u, 0u, 0u};
}

// x NCHW f32 -> xp padded NHWC bf16 (transpose via LDS tile)
__global__ __launch_bounds__(256) void prep_x(const float* __restrict__ x, bf16* __restrict__ xp) {
    int bid = blockIdx.x;
    int xc = bid & 3;  int r = bid >> 2;
    int cc = r & 15;   r >>= 4;
    int yo = r % 36;   int b = r / 36;
    int ci0 = cc * 32, xo0 = xc * 32;
    int wdt = 100 - xo0; if (wdt > 32) wdt = 32;
    __shared__ bf16 T[32 * 33];
    int t = threadIdx.x;
    int cl = t >> 5, xl = t & 31;
    if (xl < wdt) {
#pragma unroll
        for (int i = 0; i < 4; i++) {
            int ci = ci0 + cl + 8 * i;
            T[(cl + 8 * i) * 33 + xl] = (bf16)x[((size_t)(b * 512 + ci) * 36 + yo) * 100 + xo0 + xl];
        }
    }
    __syncthreads();
    if (t < 128) {
        int xo2 = t >> 2, oct = t & 3;
        if (xo2 < wdt) {
            bf16x8 vv;
#pragma unroll
            for (int j = 0; j < 8; j++) vv[j] = T[(oct * 8 + j) * 33 + xo2];
            *(bf16x8*)(xp + ((size_t)((b * YS + yo + 4) * XSZ) + xo0 + xo2 + 4) * 512 + ci0 + oct * 8) = vv;
        }
    }
}

// w1a [co][ci][3][3] f32 -> A1 [co][(ky*3+kx)*512+ci] bf16
__global__ __launch_bounds__(256) void prep_w1a(const float* __restrict__ w, bf16* __restrict__ A) {
    int co = blockIdx.x;
    __shared__ bf16 Wl[4608];           // [ci*9 + r]
    const float* src = w + (size_t)co * 4608;
    for (int v = threadIdx.x; v < 4608; v += 256) Wl[v] = (bf16)src[v];
    __syncthreads();
    bf16* dst = A + (size_t)co * 4608;
    for (int v = threadIdx.x; v < 4608; v += 256) {
        int rr = v >> 9, ci = v & 511;
        dst[v] = Wl[ci * 9 + rr];
    }
}

__global__ __launch_bounds__(256) void prep_w1b(const float* __restrict__ w, bf16* __restrict__ A) {
    int i = blockIdx.x * 256 + threadIdx.x;
    if (i < 131072) A[i] = (bf16)w[i];
}

// 4 message weights [co][ci][9] f32 -> Aw [w][t][co][ci] bf16
__global__ __launch_bounds__(256) void prep_msg(const float* __restrict__ w0, const float* __restrict__ w1,
                                                const float* __restrict__ w2m, const float* __restrict__ w3,
                                                bf16* __restrict__ Aw) {
    int idx = blockIdx.x * 256 + threadIdx.x;
    if (idx >= 4 * 147456) return;
    int w = idx / 147456, r = idx % 147456;
    int t9 = r / 16384, r2 = r % 16384;
    int co = r2 >> 7, ci = r2 & 127;
    const float* s = (w == 0) ? w0 : (w == 1) ? w1 : (w == 2) ? w2m : w3;
    Aw[idx] = (bf16)s[(co * 128 + ci) * 9 + t9];
}

__global__ __launch_bounds__(256) void prep_bn(const float* g1, const float* b1, const float* m1, const float* v1,
                                               const float* g2, const float* b2i, const float* m2, const float* v2,
                                               float* s1, float* t1, float* s2, float* t2) {
    int i = blockIdx.x * 256 + threadIdx.x;
    if (i < 1024) {
        float s = g1[i] / sqrtf(v1[i] + 1e-5f);
        s1[i] = s; t1[i] = b1[i] - m1[i] * s;
    } else if (i < 1152) {
        int c = i - 1024;
        float s = g2[c] / sqrtf(v2[c] + 1e-5f);
        s2[c] = s; t2[c] = b2i[c] - m2[c] * s;
    }
}

// ---------------- conv1: implicit-im2col GEMM, 128co x 128px tile, bf16 MFMA ----------------
__device__ __forceinline__ void c1_koff(int ch, int& k0, int& xoff) {
    int ky = ch / 48, rem = ch - ky * 48;
    int kx = rem >> 4, c0 = (rem & 15) << 5;
    k0 = (ky * 3 + kx) * 512 + c0;
    xoff = (ky * XSZ + kx) * 2048 + c0;          // (4*ky*108 + 4*kx)*512 + c0
}

__global__ __launch_bounds__(256) void conv1_gemm(const bf16* __restrict__ A, const bf16* __restrict__ xp,
                                                  const float* __restrict__ s1, const float* __restrict__ t1,
                                                  bf16* __restrict__ h1) {
    __shared__ __align__(16) bf16 As[128 * 40];
    __shared__ __align__(16) bf16 Bs[128 * 40];
    const int t = threadIdx.x;
    const int pt = blockIdx.x, ct = blockIdx.y;
    const int co0 = ct * 128, p0 = pt * 128;

    int a_off[2], b_base[2], s_lds[2];
#pragma unroll
    for (int i = 0; i < 2; i++) {
        int v = t + 256 * i;
        int row = v >> 2, oct = v & 3;
        a_off[i] = (co0 + row) * 4608 + oct * 8;
        s_lds[i] = row * 40 + oct * 8;
        int p = p0 + row;
        int b = p / 3600, rr = p % 3600;
        int y = rr / 100, xx = rr % 100;
        b_base[i] = ((b * YS + y) * XSZ + xx) * 512 + oct * 8;
    }

    const int wid = t >> 6, lane = t & 63;
    const int mbase = (wid & 1) * 64, nbase = (wid >> 1) * 64;
    const int l15 = lane & 15, q = lane >> 4;

    f32x4 acc[4][4];
#pragma unroll
    for (int i = 0; i < 4; i++)
#pragma unroll
        for (int j = 0; j < 4; j++) acc[i][j] = f32x4{0.f, 0.f, 0.f, 0.f};

    int k0, xoff;
    c1_koff(0, k0, xoff);
    uint4 av[2], bv[2];
#pragma unroll
    for (int i = 0; i < 2; i++) {
        av[i] = *(const uint4*)(A + a_off[i] + k0);
        bv[i] = *(const uint4*)(xp + b_base[i] + xoff);
    }

    for (int ch = 0; ch < 144; ch++) {
        __syncthreads();
#pragma unroll
        for (int i = 0; i < 2; i++) {
            *(uint4*)(As + s_lds[i]) = av[i];
            *(uint4*)(Bs + s_lds[i]) = bv[i];
        }
        __syncthreads();
        int nch = (ch + 1 < 144) ? ch + 1 : ch;
        c1_koff(nch, k0, xoff);
#pragma unroll
        for (int i = 0; i < 2; i++) {
            av[i] = *(const uint4*)(A + a_off[i] + k0);
            bv[i] = *(const uint4*)(xp + b_base[i] + xoff);
        }
        bf16x8 af[4], bfv[4];
#pragma unroll
        for (int mt = 0; mt < 4; mt++) af[mt] = *(const bf16x8*)(As + (mbase + mt * 16 + l15) * 40 + q * 8);
#pragma unroll
        for (int nt = 0; nt < 4; nt++) bfv[nt] = *(const bf16x8*)(Bs + (nbase + nt * 16 + l15) * 40 + q * 8);
#pragma unroll
        for (int mt = 0; mt < 4; mt++)
#pragma unroll
            for (int nt = 0; nt < 4; nt++)
                acc[mt][nt] = __builtin_amdgcn_mfma_f32_16x16x32_bf16(af[mt], bfv[nt], acc[mt][nt], 0, 0, 0);
    }

#pragma unroll
    for (int mt = 0; mt < 4; mt++) {
        int co = co0 + mbase + mt * 16 + q * 4;
        f32x4 sc = *(const f32x4*)(s1 + co);
        f32x4 tc = *(const f32x4*)(t1 + co);
#pragma unroll
        for (int nt = 0; nt < 4; nt++) {
            int p = p0 + nbase + nt * 16 + l15;
            bf16x4 o;
#pragma unroll
            for (int r = 0; r < 4; r++) {
                float v = acc[mt][nt][r] * sc[r] + tc[r];
                o[r] = (bf16)(v > 0.f ? v : 0.f);
            }
            *(bf16x4*)(h1 + (size_t)p * 1024 + co) = o;
        }
    }
}

// ---------------- conv2: 1x1 1024->128 GEMM + bn + relu, writes padded hp ----------------
__global__ __launch_bounds__(256) void conv2_gemm(const bf16* __restrict__ A2, const bf16* __restrict__ h1,
                                                  const float* __restrict__ s2, const float* __restrict__ t2,
                                                  bf16* __restrict__ hp) {
    __shared__ __align__(16) bf16 As[128 * 40];
    __shared__ __align__(16) bf16 Bs[128 * 40];
    const int t = threadIdx.x;
    const int p0 = blockIdx.x * 128;

    int a_off[2], b_off[2], s_lds[2];
#pragma unroll
    for (int i = 0; i < 2; i++) {
        int v = t + 256 * i;
        int row = v >> 2, oct = v & 3;
        a_off[i] = row * 1024 + oct * 8;
        b_off[i] = (p0 + row) * 1024 + oct * 8;
        s_lds[i] = row * 40 + oct * 8;
    }
    const int wid = t >> 6, lane = t & 63;
    const int mbase = (wid & 1) * 64, nbase = (wid >> 1) * 64;
    const int l15 = lane & 15, q = lane >> 4;

    f32x4 acc[4][4];
#pragma unroll
    for (int i = 0; i < 4; i++)
#pragma unroll
        for (int j = 0; j < 4; j++) acc[i][j] = f32x4{0.f, 0.f, 0.f, 0.f};

    uint4 av[2], bv[2];
#pragma unroll
    for (int i = 0; i < 2; i++) {
        av[i] = *(const uint4*)(A2 + a_off[i]);
        bv[i] = *(const uint4*)(h1 + b_off[i]);
    }
    for (int ch = 0; ch < 32; ch++) {
        __syncthreads();
#pragma unroll
        for (int i = 0; i < 2; i++) {
            *(uint4*)(As + s_lds[i]) = av[i];
            *(uint4*)(Bs + s_lds[i]) = bv[i];
        }
        __syncthreads();
        int c0 = (ch + 1 < 32) ? (ch + 1) * 32 : ch * 32;
#pragma unroll
        for (int i = 0; i < 2; i++) {
            av[i] = *(const uint4*)(A2 + a_off[i] + c0);
            bv[i] = *(const uint4*)(h1 + b_off[i] + c0);
        }
        bf16x8 af[4], bfv[4];
#pragma unroll
        for (int mt = 0; mt < 4; mt++) af[mt] = *(const bf16x8*)(As + (mbase + mt * 16 + l15) * 40 + q * 8);
#pragma unroll
        for (int nt = 0; nt < 4; nt++) bfv[nt] = *(const bf16x8*)(Bs + (nbase + nt * 16 + l15) * 40 + q * 8);
#pragma unroll
        for (int mt = 0; mt < 4; mt++)
#pragma unroll
            for (int nt = 0; nt < 4; nt++)
                acc[mt][nt] = __builtin_amdgcn_mfma_f32_16x16x32_bf16(af[mt], bfv[nt], acc[mt][nt], 0, 0, 0);
    }
#pragma unroll
    for (int mt = 0; mt < 4; mt++) {
        int co = mbase + mt * 16 + q * 4;
        f32x4 sc = *(const f32x4*)(s2 + co);
        f32x4 tc = *(const f32x4*)(t2 + co);
#pragma unroll
        for (int nt = 0; nt < 4; nt++) {
            int p = p0 + nbase + nt * 16 + l15;
            int b = p / 3600, rr = p % 3600;
            int y = rr / 100, xx = rr % 100;
            bf16x4 o;
#pragma unroll
            for (int r = 0; r < 4; r++) {
                float v = acc[mt][nt][r] * sc[r] + tc[r];
                o[r] = (bf16)(v > 0.f ? v : 0.f);
            }
            *(bf16x4*)(hp + (size_t)((b * YS + y + 4) * XSZ + xx + 4) * 128 + co) = o;
        }
    }
}

// ---------------- message passes: per-batch persistent block, MFMA scan ----------------
// AX=2: scan rows (conv along W, N=100);  AX=3: scan cols (conv along H, N=36)
template <int AX, int RV>
__global__ __launch_bounds__(256) void msg_pass(const bf16* __restrict__ Aw, bf16* __restrict__ hp) {
    constexpr int ROWS = (AX == 2) ? 120 : 56;
    constexpr int NT = (AX == 2) ? 7 : 3;
    constexpr int STEPS = (AX == 2) ? NH : NW;
    constexpr int NLIM = (AX == 2) ? NW : NH;
    __shared__ __align__(16) bf16 Rb[ROWS * 136];
    const int b = blockIdx.x;
    const int t = threadIdx.x;
    const int wid = t >> 6, lane = t & 63, l15 = lane & 15, q = lane >> 4;
    bf16* hpb = hp + (size_t)b * YS * XSZ * 128;

    // stage the first (unchanged) line into LDS, including zero borders
    if (AX == 2) {
        int ys0 = RV ? 39 : 4;
        for (int v = t; v < XSZ * 16; v += 256) {
            int xs = v >> 4, oct = v & 15;
            *(uint4*)(Rb + xs * 136 + oct * 8) = *(const uint4*)(hpb + ((size_t)ys0 * XSZ + xs) * 128 + oct * 8);
        }
    } else {
        int xs0 = RV ? 103 : 4;
        for (int v = t; v < YS * 16; v += 256) {
            int ys = v >> 4, oct = v & 15;
            *(uint4*)(Rb + ys * 136 + oct * 8) = *(const uint4*)(hpb + ((size_t)ys * XSZ + xs0) * 128 + oct * 8);
        }
    }

    for (int s = 1; s < STEPS; s++) {
        int pos = RV ? (STEPS - 1 - s) : s;
        __syncthreads();  // prev line (LDS) ready

        f32x4 acc[2][NT];
#pragma unroll
        for (int mt = 0; mt < 2; mt++)
#pragma unroll
            for (int nt = 0; nt < NT; nt++) acc[mt][nt] = f32x4{0.f, 0.f, 0.f, 0.f};

        bf16x8 acur[2], anxt[2];
#pragma unroll
        for (int mt = 0; mt < 2; mt++)
            acur[mt] = *(const bf16x8*)(Aw + (size_t)(0 * 128 + wid * 32 + mt * 16 + l15) * 128 + 0 + q * 8);

        for (int ch = 0; ch < 36; ch++) {
            int nc = (ch < 35) ? ch + 1 : ch;
            int nt9 = nc >> 2, nc0 = (nc & 3) << 5;
#pragma unroll
            for (int mt = 0; mt < 2; mt++)
                anxt[mt] = *(const bf16x8*)(Aw + (size_t)(nt9 * 128 + wid * 32 + mt * 16 + l15) * 128 + nc0 + q * 8);
            int t9 = ch >> 2, c0 = (ch & 3) << 5;
            bf16x8 bfv[NT];
#pragma unroll
            for (int nt = 0; nt < NT; nt++) {
                int n = nt * 16 + l15;
                bfv[nt] = *(const bf16x8*)(Rb + (n + t9) * 136 + c0 + q * 8);
            }
#pragma unroll
            for (int mt = 0; mt < 2; mt++)
#pragma unroll
                for (int nt = 0; nt < NT; nt++)
                    acc[mt][nt] = __builtin_amdgcn_mfma_f32_16x16x32_bf16(acur[mt], bfv[nt], acc[mt][nt], 0, 0, 0);
            acur[0] = anxt[0];
            acur[1] = anxt[1];
        }
        __syncthreads();  // all reads of Rb done before overwriting

#pragma unroll
        for (int mt = 0; mt < 2; mt++) {
            int co = wid * 32 + mt * 16 + q * 4;
#pragma unroll
            for (int nt = 0; nt < NT; nt++) {
                int n = nt * 16 + l15;
                if (n < NLIM) {
                    size_t g = (AX == 2) ? ((size_t)(pos + 4) * XSZ + (n + 4)) * 128 + co
                                         : ((size_t)(n + 4) * XSZ + (pos + 4)) * 128 + co;
                    int rl = (n + 4) * 136 + co;
                    bf16x4 cur = *(const bf16x4*)(hpb + g);
                    bf16x4 o;
#pragma unroll
                    for (int r = 0; r < 4; r++) {
                        float v = acc[mt][nt][r];
                        v = v > 0.f ? v : 0.f;
                        o[r] = (bf16)((float)cur[r] + v);
                    }
                    *(bf16x4*)(hpb + g) = o;
                    *(bf16x4*)(Rb + rl) = o;
                }
            }
        }
    }
}

// ---------------- conv3 (1x1 128->5) + bias + softmax ----------------
__global__ __launch_bounds__(256) void conv3_softmax(const bf16* __restrict__ hp, const float* __restrict__ w2,
                                                     const float* __restrict__ b2, float* __restrict__ h5,
                                                     float* __restrict__ Pp) {
    int idx = blockIdx.x * 256 + threadIdx.x;
    if (idx >= PIX) return;
    int b = idx / 3600, rr = idx % 3600;
    int y = rr / 100, xx = rr % 100;
    const bf16* src = hp + ((size_t)(b * YS + y + 4) * XSZ + xx + 4) * 128;
    float a[5] = {b2[0], b2[1], b2[2], b2[3], b2[4]};
    for (int c8 = 0; c8 < 128; c8 += 8) {
        bf16x8 hv = *(const bf16x8*)(src + c8);
#pragma unroll
        for (int j = 0; j < 8; j++) {
            float hf = (float)hv[j];
            int c = c8 + j;
#pragma unroll
            for (int o = 0; o < 5; o++) a[o] += hf * w2[o * 128 + c];
        }
    }
    float mx = a[0];
#pragma unroll
    for (int o = 1; o < 5; o++) mx = a[o] > mx ? a[o] : mx;
    float e[5], sum = 0.f;
#pragma unroll
    for (int o = 0; o < 5; o++) { e[o] = expf(a[o] - mx); sum += e[o]; }
    float inv = 1.f / sum;
#pragma unroll
    for (int o = 0; o < 5; o++) {
        h5[(size_t)(b * 5 + o) * 3600 + rr] = a[o];
        Pp[(size_t)(b * 5 + o) * 3600 + rr] = e[o] * inv;
    }
}

// ---------------- 2x2 avg pool -> F [8][4500] ----------------
__global__ __launch_bounds__(256) void pool_k(const float* __restrict__ Pp, float* __restrict__ F) {
    int idx = blockIdx.x * 256 + threadIdx.x;
    if (idx >= 36000) return;
    int xxp = idx % 50, r = idx / 50;
    int yyp = r % 18, bj = r / 18;
    int b = bj / 5, j = bj % 5;
    const float* Pb = Pp + (size_t)bj * 3600;
    float v = 0.25f * (Pb[(2 * yyp) * 100 + 2 * xxp] + Pb[(2 * yyp) * 100 + 2 * xxp + 1] +
                       Pb[(2 * yyp + 1) * 100 + 2 * xxp] + Pb[(2 * yyp + 1) * 100 + 2 * xxp + 1]);
    F[(size_t)b * 4500 + j * 900 + yyp * 50 + xxp] = v;
}

// ---------------- fc1 (4500->128) + relu ----------------
__global__ __launch_bounds__(64) void fc1_k(const float* __restrict__ F, const float* __restrict__ w,
                                            const float* __restrict__ bias, float* __restrict__ G) {
    int co = blockIdx.x;
    int lane = threadIdx.x;
    const float* wr = w + (size_t)co * 4500;
    float a[8] = {0.f, 0.f, 0.f, 0.f, 0.f, 0.f, 0.f, 0.f};
    for (int k = lane; k < 4500; k += 64) {
        float wv = wr[k];
#pragma unroll
        for (int b = 0; b < 8; b++) a[b] += wv * F[b * 4500 + k];
    }
#pragma unroll
    for (int b = 0; b < 8; b++) {
        float r = a[b];
        for (int off = 32; off; off >>= 1) r += __shfl_down(r, off);
        if (lane == 0) {
            float v = r + bias[co];
            G[b * 128 + co] = v > 0.f ? v : 0.f;
        }
    }
}

// ---------------- fc2 (128->4) + sigmoid -> out tail ----------------
__global__ __launch_bounds__(64) void fc2_k(const float* __restrict__ G, const float* __restrict__ w,
                                            const float* __restrict__ bias, float* __restrict__ out) {
    int t = threadIdx.x;
    if (t >= 32) return;
    int b = t >> 2, j = t & 3;
    float a = bias[j];
    for (int c = 0; c < 128; c++) a += G[b * 128 + c] * w[j * 128 + c];
    out[9216000 + b * 4 + j] = 1.f / (1.f + expf(-a));
}

// ---------------- bilinear upsample x8 (align-corners grid) ----------------
__global__ __launch_bounds__(256) void upsample_k(const float* __restrict__ h5, float* __restrict__ out) {
    int idx = blockIdx.x * 256 + threadIdx.x;
    if (idx >= 2304000) return;
    int xq = idx % 200, r = idx / 200;
    int yo = r % 288, bj = r / 288;
    const float* src = h5 + (size_t)bj * 3600;
    float py = yo * (35.0f / 287.0f);
    int i0 = (int)py; if (i0 > 34) i0 = 34;
    float fh = py - (float)i0;
    const float* r0 = src + i0 * 100;
    const float* r1 = r0 + 100;
    float4 o;
    float res[4];
#pragma unroll
    for (int e = 0; e < 4; e++) {
        int xo = xq * 4 + e;
        float px = xo * (99.0f / 799.0f);
        int j0 = (int)px; if (j0 > 98) j0 = 98;
        float fw = px - (float)j0;
        float aa = r0[j0] * (1.f - fh) + r1[j0] * fh;
        float bb = r0[j0 + 1] * (1.f - fh) + r1[j0 + 1] * fh;
        res[e] = aa * (1.f - fw) + bb * fw;
    }
    o.x = res[0]; o.y = res[1]; o.z = res[2]; o.w = res[3];
    *(float4*)(out + (size_t)idx * 4) = o;
}

// ---------------- launcher ----------------
extern "C" void kernel_launch(void* const* d_in, const int* in_sizes, int n_in,
                              void* d_out, int out_size, void* d_ws, size_t ws_size,
                              hipStream_t stream) {
    (void)in_sizes; (void)n_in; (void)out_size; (void)ws_size;
    const float* x    = (const float*)d_in[0];
    const float* w1a  = (const float*)d_in[1];
    const float* bn1g = (const float*)d_in[2];
    const float* bn1b = (const float*)d_in[3];
    const float* bn1m = (const float*)d_in[4];
    const float* bn1v = (const float*)d_in[5];
    const float* w1b  = (const float*)d_in[6];
    const float* bn2g = (const float*)d_in[7];
    const float* bn2b = (const float*)d_in[8];
    const float* bn2m = (const float*)d_in[9];
    const float* bn2v = (const float*)d_in[10];
    const float* wud  = (const float*)d_in[11];
    const float* wdu  = (const float*)d_in[12];
    const float* wlr  = (const float*)d_in[13];
    const float* wrl  = (const float*)d_in[14];
    const float* w2   = (const float*)d_in[15];
    const float* b2   = (const float*)d_in[16];
    const float* fc1w = (const float*)d_in[17];
    const float* fc1b = (const float*)d_in[18];
    const float* fc2w = (const float*)d_in[19];
    const float* fc2b = (const float*)d_in[20];
    float* out = (float*)d_out;
    char* ws = (char*)d_ws;
    bf16* xp = (bf16*)(ws + OFF_XP);
    bf16* hp = (bf16*)(ws + OFF_HP);
    bf16* A1 = (bf16*)(ws + OFF_A1);
    bf16* A2 = (bf16*)(ws + OFF_A2);
    bf16* Aw = (bf16*)(ws + OFF_AW);
    bf16* h1 = (bf16*)(ws + OFF_H1);
    float* s1 = (float*)(ws + OFF_S1);
    float* t1 = (float*)(ws + OFF_T1);
    float* s2 = (float*)(ws + OFF_S2);
    float* t2 = (float*)(ws + OFF_T2);
    float* h5 = (float*)(ws + OFF_H5);
    float* Pp = (float*)(ws + OFF_P);
    float* Ff = (float*)(ws + OFF_F);
    float* Gg = (float*)(ws + OFF_G);

    int nzero = (int)((SZ_XP + SZ_HP) / 16);
    zero_k<<<(nzero + 255) / 256, 256, 0, stream>>>((uint4*)ws, nzero);
    prep_x<<<18432, 256, 0, stream>>>(x, xp);
    prep_w1a<<<1024, 256, 0, stream>>>(w1a, A1);
    prep_w1b<<<512, 256, 0, stream>>>(w1b, A2);
    prep_msg<<<2304, 256, 0, stream>>>(wud, wdu, wlr, wrl, Aw);
    prep_bn<<<5, 256, 0, stream>>>(bn1g, bn1b, bn1m, bn1v, bn2g, bn2b, bn2m, bn2v, s1, t1, s2, t2);

    conv1_gemm<<<dim3(225, 8), 256, 0, stream>>>(A1, xp, s1, t1, h1);
    conv2_gemm<<<225, 256, 0, stream>>>(A2, h1, s2, t2, hp);

    msg_pass<2, 0><<<NB, 256, 0, stream>>>(Aw + 0 * 147456, hp);
    msg_pass<2, 1><<<NB, 256, 0, stream>>>(Aw + 1 * 147456, hp);
    msg_pass<3, 0><<<NB, 256, 0, stream>>>(Aw + 2 * 147456, hp);
    msg_pass<3, 1><<<NB, 256, 0, stream>>>(Aw + 3 * 147456, hp);

    conv3_softmax<<<113, 256, 0, stream>>>(hp, w2, b2, h5, Pp);
    pool_k<<<141, 256, 0, stream>>>(Pp, Ff);
    fc1_k<<<128, 64, 0, stream>>>(Ff, fc1w, fc1b, Gg);
    fc2_k<<<1, 64, 0, stream>>>(Gg, fc2w, fc2b, out);
    upsample_k<<<9000, 256, 0, stream>>>(h5, out);
}